// Round 1
// baseline (612.627 us; speedup 1.0000x reference)
//
#include <hip/hip_runtime.h>

// Problem constants
// x: (8, 512, 32, 32) fp32 -> (B=8, C=512, T=1024)
// NUM_GROUPS=32 (16 ch/group), NUM_HEADS=8 (ch=64), N_BITS=8, EPS=1e-5

static constexpr int B_ = 8;
static constexpr int C_ = 512;
static constexpr int T_ = 1024;

// ws layout (floats):
//  [0, 4M)      : h (groupnorm out), later reused as attention output a
//  [4M, 16M)    : qkv (B, 1536, T)
//  [16M, +12)   : 6 encoded min/max slots (uint) + spare
static constexpr size_t HOFF   = 0;
static constexpr size_t QKVOFF = (size_t)B_ * C_ * T_;                 // 4,194,304
static constexpr size_t MMOFF  = QKVOFF + (size_t)B_ * 3 * C_ * T_;    // 16,777,216

// ---- float <-> total-ordered unsigned encoding for atomic min/max ----
__device__ __forceinline__ unsigned encf(float f) {
    unsigned u = __float_as_uint(f);
    return (u & 0x80000000u) ? ~u : (u | 0x80000000u);
}
__device__ __forceinline__ float decf(unsigned e) {
    unsigned u = (e & 0x80000000u) ? (e & 0x7fffffffu) : ~e;
    return __uint_as_float(u);
}

// fake-quant dequantize: (clip(round(x/s)+zp,0,255)-zp)*s ; rintf = round-half-even = jnp.round
__device__ __forceinline__ float dqf(float x, float s, float zp) {
    float q = rintf(x / s) + zp;
    q = fminf(fmaxf(q, 0.0f), 255.0f);
    return (q - zp) * s;
}

// ---------------- GroupNorm ----------------
// grid: 256 blocks = (b, g); block: 256 threads. 16 channels x 1024 T contiguous.
__global__ __launch_bounds__(256) void gn_kernel(const float* __restrict__ x,
                                                 const float* __restrict__ w,
                                                 const float* __restrict__ bv,
                                                 float* __restrict__ h) {
    int blk = blockIdx.x;
    int b = blk >> 5, g = blk & 31;
    const float* xp = x + ((size_t)(b * C_ + g * 16)) * T_;
    float* hp = h + ((size_t)(b * C_ + g * 16)) * T_;
    int tid = threadIdx.x;

    float sum = 0.f, ss = 0.f;
#pragma unroll
    for (int i = 0; i < 16; ++i) {
        float4 v = *(const float4*)(xp + (size_t)i * 1024 + tid * 4);
        sum += v.x + v.y + v.z + v.w;
        ss  += v.x * v.x + v.y * v.y + v.z * v.z + v.w * v.w;
    }
#pragma unroll
    for (int m = 1; m < 64; m <<= 1) {
        sum += __shfl_xor(sum, m);
        ss  += __shfl_xor(ss, m);
    }
    __shared__ float s1[4], s2[4];
    int wid = tid >> 6;
    if ((tid & 63) == 0) { s1[wid] = sum; s2[wid] = ss; }
    __syncthreads();
    sum = s1[0] + s1[1] + s1[2] + s1[3];
    ss  = s2[0] + s2[1] + s2[2] + s2[3];
    float mean = sum * (1.0f / 16384.0f);
    float var  = ss * (1.0f / 16384.0f) - mean * mean;
    float rstd = rsqrtf(var + 1e-5f);
#pragma unroll
    for (int i = 0; i < 16; ++i) {
        int c = g * 16 + i;
        float wc = w[c], bc = bv[c];
        float4 v = *(const float4*)(xp + (size_t)i * 1024 + tid * 4);
        float4 o;
        o.x = (v.x - mean) * rstd * wc + bc;
        o.y = (v.y - mean) * rstd * wc + bc;
        o.z = (v.z - mean) * rstd * wc + bc;
        o.w = (v.w - mean) * rstd * wc + bc;
        *(float4*)(hp + (size_t)i * 1024 + tid * 4) = o;
    }
}

// ---------------- min/max slot init ----------------
__global__ void init_mm(unsigned* mm) {
    int t = threadIdx.x;
    if (t < 3) { mm[2 * t] = 0xFFFFFFFFu; mm[2 * t + 1] = 0u; }
}

// ---------------- GEMM: out[b,o,t] = sum_c W[o,c]*X[b,c,t] + bias[o] (+resid) ----------------
// block: 256 thr, tile 64(o) x 64(t), K=512 in steps of 16.
template <bool MINMAX, bool RESID>
__global__ __launch_bounds__(256) void gemm_kernel(const float* __restrict__ W,
                                                   const float* __restrict__ X,
                                                   const float* __restrict__ bias,
                                                   const float* __restrict__ resid,
                                                   float* __restrict__ out,
                                                   int M, unsigned* mm) {
    __shared__ float sW[16][68];  // [k][o_local]
    __shared__ float sX[16][68];  // [k][t_local]
    int tid = threadIdx.x;
    int tx = tid & 15, ty = tid >> 4;
    int o0 = blockIdx.x * 64, t0 = blockIdx.y * 64, b = blockIdx.z;
    const float* Wp = W + (size_t)o0 * 512;
    const float* Xp = X + ((size_t)b * 512) * 1024 + t0;

    float acc[4][4] = {};
    int wrow = tid >> 2, wc4 = (tid & 3) * 4;
    int xrow = tid >> 4, xc4 = (tid & 15) * 4;

    for (int k0 = 0; k0 < 512; k0 += 16) {
        float4 wv = *(const float4*)(Wp + (size_t)wrow * 512 + k0 + wc4);
        float4 xv = *(const float4*)(Xp + (size_t)(k0 + xrow) * 1024 + xc4);
        sW[wc4 + 0][wrow] = wv.x;
        sW[wc4 + 1][wrow] = wv.y;
        sW[wc4 + 2][wrow] = wv.z;
        sW[wc4 + 3][wrow] = wv.w;
        *(float4*)&sX[xrow][xc4] = xv;
        __syncthreads();
#pragma unroll
        for (int k = 0; k < 16; ++k) {
            float4 a4 = *(const float4*)&sW[k][ty * 4];
            float4 b4 = *(const float4*)&sX[k][tx * 4];
            float ar[4] = {a4.x, a4.y, a4.z, a4.w};
            float br[4] = {b4.x, b4.y, b4.z, b4.w};
#pragma unroll
            for (int i = 0; i < 4; ++i)
#pragma unroll
                for (int j = 0; j < 4; ++j) acc[i][j] = fmaf(ar[i], br[j], acc[i][j]);
        }
        __syncthreads();
    }

    float mn = 1e30f, mx = -1e30f;
#pragma unroll
    for (int i = 0; i < 4; ++i) {
        int row = o0 + ty * 4 + i;
        float bi = bias[row];
        float4 rs;
        if (RESID) rs = *(const float4*)(resid + ((size_t)b * M + row) * 1024 + t0 + tx * 4);
#pragma unroll
        for (int j = 0; j < 4; ++j) {
            float v = acc[i][j] + bi;
            if (MINMAX) { mn = fminf(mn, v); mx = fmaxf(mx, v); }
            if (RESID) v += (&rs.x)[j];
            acc[i][j] = v;
        }
        float4 o = {acc[i][0], acc[i][1], acc[i][2], acc[i][3]};
        *(float4*)(out + ((size_t)b * M + row) * 1024 + t0 + tx * 4) = o;
    }

    if (MINMAX) {
#pragma unroll
        for (int m = 1; m < 64; m <<= 1) {
            mn = fminf(mn, __shfl_xor(mn, m));
            mx = fmaxf(mx, __shfl_xor(mx, m));
        }
        __shared__ float smn[4], smx[4];
        int wid = tid >> 6;
        if ((tid & 63) == 0) { smn[wid] = mn; smx[wid] = mx; }
        __syncthreads();
        if (tid == 0) {
            mn = fminf(fminf(smn[0], smn[1]), fminf(smn[2], smn[3]));
            mx = fmaxf(fmaxf(smx[0], smx[1]), fmaxf(smx[2], smx[3]));
            int id = blockIdx.x % 3;  // 64-aligned o-tiles cycle q,k,v (192 = 3*64)
            atomicMin(&mm[2 * id], encf(mn));
            atomicMax(&mm[2 * id + 1], encf(mx));
        }
    }
}

// ---------------- Attention (flash-style, fp32) ----------------
// grid: (bh=64, ttile=16); block 256 thr. Per block: 64 t-rows, loop 16 s-tiles of 64.
__global__ __launch_bounds__(256) void attn_kernel(const float* __restrict__ qkv,
                                                   const unsigned* __restrict__ mm,
                                                   float* __restrict__ aout) {
    int bh = blockIdx.x, tt = blockIdx.y;
    int b = bh >> 3, hh = bh & 7;
    int t0 = tt * 64;
    const float* qb = qkv + ((size_t)(b * 1536 + hh * 192)) * 1024;
    const float* kb = qb + (size_t)64 * 1024;
    const float* vb = qb + (size_t)128 * 1024;

    // quant params (computed redundantly per thread; cheap)
    float qsc, qzp, ksc, kzp, vsc, vzp;
    {
        float mn = fminf(decf(mm[0]), 0.f), mx = fmaxf(decf(mm[1]), 0.f);
        qsc = fmaxf((mx - mn) * (1.0f / 255.0f), 1e-8f);
        qzp = rintf(-mn / qsc);
        mn = fminf(decf(mm[2]), 0.f); mx = fmaxf(decf(mm[3]), 0.f);
        ksc = fmaxf((mx - mn) * (1.0f / 255.0f), 1e-8f);
        kzp = rintf(-mn / ksc);
        mn = fminf(decf(mm[4]), 0.f); mx = fmaxf(decf(mm[5]), 0.f);
        vsc = fmaxf((mx - mn) * (1.0f / 255.0f), 1e-8f);
        vzp = rintf(-mn / vsc);
    }
    const float ascale = 0.35355339059327373f;  // 1/sqrt(sqrt(64))

    __shared__ float qt[64][68];   // [c][t]
    __shared__ float kt[64][68];   // [c][s]
    __shared__ float vtT[64][68];  // [s][c]
    __shared__ float pt[64][68];   // [s][t]
    __shared__ float ft[64];
    __shared__ float lt[64];

    int tid = threadIdx.x;
    int tx = tid & 15, ty = tid >> 4;
    int lrow = tid >> 4;          // 0..15
    int lc4 = (tid & 15) * 4;     // 0..60

    // load q tile (dequant + attn scale)
#pragma unroll
    for (int r = 0; r < 4; ++r) {
        int row = r * 16 + lrow;
        float4 v = *(const float4*)(qb + (size_t)row * 1024 + t0 + lc4);
        float4 o;
        o.x = dqf(v.x, qsc, qzp) * ascale;
        o.y = dqf(v.y, qsc, qzp) * ascale;
        o.z = dqf(v.z, qsc, qzp) * ascale;
        o.w = dqf(v.w, qsc, qzp) * ascale;
        *(float4*)&qt[row][lc4] = o;
    }

    float m_[4], l_[4], acc[4][4] = {};
#pragma unroll
    for (int i = 0; i < 4; ++i) { m_[i] = -1e30f; l_[i] = 0.f; }

    for (int st = 0; st < 16; ++st) {
        int s0 = st * 64;
#pragma unroll
        for (int r = 0; r < 4; ++r) {
            int row = r * 16 + lrow;
            float4 kv4 = *(const float4*)(kb + (size_t)row * 1024 + s0 + lc4);
            float4 o;
            o.x = dqf(kv4.x, ksc, kzp) * ascale;
            o.y = dqf(kv4.y, ksc, kzp) * ascale;
            o.z = dqf(kv4.z, ksc, kzp) * ascale;
            o.w = dqf(kv4.w, ksc, kzp) * ascale;
            *(float4*)&kt[row][lc4] = o;
            float4 vv4 = *(const float4*)(vb + (size_t)row * 1024 + s0 + lc4);
            vtT[lc4 + 0][row] = dqf(vv4.x, vsc, vzp);
            vtT[lc4 + 1][row] = dqf(vv4.y, vsc, vzp);
            vtT[lc4 + 2][row] = dqf(vv4.z, vsc, vzp);
            vtT[lc4 + 3][row] = dqf(vv4.w, vsc, vzp);
        }
        __syncthreads();

        // scores (t x s)
        float sc[4][4] = {};
#pragma unroll
        for (int c = 0; c < 64; ++c) {
            float4 qv = *(const float4*)&qt[c][ty * 4];
            float4 kv = *(const float4*)&kt[c][tx * 4];
            float qr[4] = {qv.x, qv.y, qv.z, qv.w};
            float kr[4] = {kv.x, kv.y, kv.z, kv.w};
#pragma unroll
            for (int i = 0; i < 4; ++i)
#pragma unroll
                for (int j = 0; j < 4; ++j) sc[i][j] = fmaf(qr[i], kr[j], sc[i][j]);
        }

        // online softmax update
        float fnew[4];
#pragma unroll
        for (int i = 0; i < 4; ++i) {
            float rm = fmaxf(fmaxf(sc[i][0], sc[i][1]), fmaxf(sc[i][2], sc[i][3]));
#pragma unroll
            for (int m = 1; m < 16; m <<= 1) rm = fmaxf(rm, __shfl_xor(rm, m));
            float mn2 = fmaxf(m_[i], rm);
            float f = __expf(m_[i] - mn2);
            float rs = 0.f;
#pragma unroll
            for (int j = 0; j < 4; ++j) {
                float p = __expf(sc[i][j] - mn2);
                sc[i][j] = p;
                rs += p;
            }
#pragma unroll
            for (int m = 1; m < 16; m <<= 1) rs += __shfl_xor(rs, m);
            l_[i] = l_[i] * f + rs;
            m_[i] = mn2;
            fnew[i] = f;
        }
        if (tx == 0) {
#pragma unroll
            for (int i = 0; i < 4; ++i) ft[ty * 4 + i] = fnew[i];
        }
#pragma unroll
        for (int i = 0; i < 4; ++i)
#pragma unroll
            for (int j = 0; j < 4; ++j) pt[tx * 4 + j][ty * 4 + i] = sc[i][j];
        __syncthreads();

        // PV: acc[c][t] = acc*f[t] + sum_s v[c][s]*p[s][t]
        float4 f4 = *(const float4*)&ft[tx * 4];
        float fj[4] = {f4.x, f4.y, f4.z, f4.w};
#pragma unroll
        for (int i = 0; i < 4; ++i)
#pragma unroll
            for (int j = 0; j < 4; ++j) acc[i][j] *= fj[j];
#pragma unroll
        for (int s = 0; s < 64; ++s) {
            float4 vv = *(const float4*)&vtT[s][ty * 4];
            float4 pv = *(const float4*)&pt[s][tx * 4];
            float vr[4] = {vv.x, vv.y, vv.z, vv.w};
            float pr[4] = {pv.x, pv.y, pv.z, pv.w};
#pragma unroll
            for (int i = 0; i < 4; ++i)
#pragma unroll
                for (int j = 0; j < 4; ++j) acc[i][j] = fmaf(vr[i], pr[j], acc[i][j]);
        }
        __syncthreads();
    }

    if (tx == 0) {
#pragma unroll
        for (int i = 0; i < 4; ++i) lt[ty * 4 + i] = l_[i];
    }
    __syncthreads();
    float4 l4 = *(const float4*)&lt[tx * 4];
    float rl[4] = {1.0f / l4.x, 1.0f / l4.y, 1.0f / l4.z, 1.0f / l4.w};
    float* op = aout + ((size_t)(b * 512 + hh * 64)) * 1024 + t0;
#pragma unroll
    for (int i = 0; i < 4; ++i) {
        int crow = ty * 4 + i;
        float4 o = {acc[i][0] * rl[0], acc[i][1] * rl[1], acc[i][2] * rl[2], acc[i][3] * rl[3]};
        *(float4*)(op + (size_t)crow * 1024 + tx * 4) = o;
    }
}

extern "C" void kernel_launch(void* const* d_in, const int* in_sizes, int n_in,
                              void* d_out, int out_size, void* d_ws, size_t ws_size,
                              hipStream_t stream) {
    const float* x      = (const float*)d_in[0];
    const float* gn_w   = (const float*)d_in[1];
    const float* gn_b   = (const float*)d_in[2];
    const float* qkv_w  = (const float*)d_in[3];
    const float* qkv_b  = (const float*)d_in[4];
    const float* proj_w = (const float*)d_in[5];
    const float* proj_b = (const float*)d_in[6];
    float* ws  = (float*)d_ws;
    float* h   = ws + HOFF;       // h, later reused as attention output a
    float* qkv = ws + QKVOFF;
    unsigned* mm = (unsigned*)(ws + MMOFF);
    float* out = (float*)d_out;

    // 1. GroupNorm -> h
    gn_kernel<<<dim3(256), dim3(256), 0, stream>>>(x, gn_w, gn_b, h);
    // 2. init min/max slots
    init_mm<<<dim3(1), dim3(64), 0, stream>>>(mm);
    // 3. QKV GEMM + bias, track per-tensor min/max of q/k/v
    gemm_kernel<true, false><<<dim3(24, 16, 8), dim3(256), 0, stream>>>(
        qkv_w, h, qkv_b, nullptr, qkv, 1536, mm);
    // 4. fused fake-quant + attention -> a (reuses h buffer)
    attn_kernel<<<dim3(64, 16), dim3(256), 0, stream>>>(qkv, mm, h);
    // 5. proj GEMM + bias + residual -> out
    gemm_kernel<false, true><<<dim3(8, 16, 8), dim3(256), 0, stream>>>(
        proj_w, h, proj_b, x, out, 512, nullptr);
}

// Round 2
// 147.432 us; speedup vs baseline: 4.1553x; 4.1553x over previous
//
#include <hip/hip_runtime.h>

typedef __attribute__((ext_vector_type(8))) __bf16 bf16x8;
typedef __attribute__((ext_vector_type(4))) __bf16 bf16x4;
typedef __attribute__((ext_vector_type(4))) float  f32x4;

// Problem: x (8,512,32,32) fp32 -> B=8, C=512, T=1024; 32 groups; 8 heads (ch=64)

// ws layout (bytes)
static constexpr size_t QKV_OFF = 0;                         // fp32 (8,1536,1024)  48 MB
static constexpr size_t HT_OFF  = 50331648;                  // bf16 (8,1024,512)    8 MB (hT, later aT)
static constexpr size_t WQ_OFF  = HT_OFF + 8388608;          // bf16 (1536,512)
static constexpr size_t WP_OFF  = WQ_OFF + 1572864;          // bf16 (512,512)
static constexpr size_t MM_OFF  = WP_OFF + 524288;           // 6 x u32 min/max slots

__device__ __forceinline__ unsigned encf(float f) {
    unsigned u = __float_as_uint(f);
    return (u & 0x80000000u) ? ~u : (u | 0x80000000u);
}
__device__ __forceinline__ float decf(unsigned e) {
    unsigned u = (e & 0x80000000u) ? (e & 0x7fffffffu) : ~e;
    return __uint_as_float(u);
}
// integer-valued dequant core: clip(rint(x/s)+zp,0,255)-zp == clip(rint(x/s), -zp, 255-zp)
__device__ __forceinline__ float dqi(float x, float inv_s, float zp) {
    float y = rintf(x * inv_s);
    return fminf(fmaxf(y, -zp), 255.0f - zp);
}
__device__ __forceinline__ f32x4 mfma16(bf16x8 a, bf16x8 b, f32x4 c) {
    return __builtin_amdgcn_mfma_f32_16x16x32_bf16(a, b, c, 0, 0, 0);
}

// ---------------- weight fp32 -> bf16 convert ----------------
__global__ __launch_bounds__(256) void conv_bf16(const float* __restrict__ src,
                                                 __bf16* __restrict__ dst, int n4) {
    int i = blockIdx.x * 256 + threadIdx.x;
    if (i < n4) {
        float4 v = ((const float4*)src)[i];
        bf16x4 o = {(__bf16)v.x, (__bf16)v.y, (__bf16)v.z, (__bf16)v.w};
        ((bf16x4*)dst)[i] = o;
    }
}

// ---------------- GroupNorm -> hT bf16 (B,T,C) ----------------
__global__ __launch_bounds__(256) void gn_kernel(const float* __restrict__ x,
                                                 const float* __restrict__ w,
                                                 const float* __restrict__ bv,
                                                 __bf16* __restrict__ hT) {
    int blk = blockIdx.x;
    int b = blk >> 5, g = blk & 31;
    const float* xp = x + (size_t)(b * 512 + g * 16) * 1024;
    int tid = threadIdx.x;

    float sum = 0.f, ss = 0.f;
#pragma unroll
    for (int i = 0; i < 16; ++i) {
        float4 v = *(const float4*)(xp + (size_t)i * 1024 + tid * 4);
        sum += v.x + v.y + v.z + v.w;
        ss  += v.x * v.x + v.y * v.y + v.z * v.z + v.w * v.w;
    }
#pragma unroll
    for (int m = 1; m < 64; m <<= 1) {
        sum += __shfl_xor(sum, m);
        ss  += __shfl_xor(ss, m);
    }
    __shared__ float s1[4], s2[4];
    int wid = tid >> 6;
    if ((tid & 63) == 0) { s1[wid] = sum; s2[wid] = ss; }
    __syncthreads();
    sum = s1[0] + s1[1] + s1[2] + s1[3];
    ss  = s2[0] + s2[1] + s2[2] + s2[3];
    float mean = sum * (1.0f / 16384.0f);
    float var  = ss * (1.0f / 16384.0f) - mean * mean;
    float rstd = rsqrtf(var + 1e-5f);

    // transposed bf16 write: thread covers 4 c at fixed t
    int cl = ((tid >> 4) & 3) * 4;                 // 0,4,8,12
    int tb = (tid & 15) + ((tid >> 6) << 4);       // 0..63
    float wc[4], bc[4];
#pragma unroll
    for (int j = 0; j < 4; ++j) { wc[j] = w[g * 16 + cl + j]; bc[j] = bv[g * 16 + cl + j]; }
    __bf16* hp = hT + (size_t)b * 1024 * 512 + g * 16 + cl;
#pragma unroll
    for (int r = 0; r < 16; ++r) {
        int t = tb + r * 64;
        float o0 = (xp[(size_t)(cl + 0) * 1024 + t] - mean) * rstd * wc[0] + bc[0];
        float o1 = (xp[(size_t)(cl + 1) * 1024 + t] - mean) * rstd * wc[1] + bc[1];
        float o2 = (xp[(size_t)(cl + 2) * 1024 + t] - mean) * rstd * wc[2] + bc[2];
        float o3 = (xp[(size_t)(cl + 3) * 1024 + t] - mean) * rstd * wc[3] + bc[3];
        bf16x4 ob = {(__bf16)o0, (__bf16)o1, (__bf16)o2, (__bf16)o3};
        *(bf16x4*)(hp + (size_t)t * 512) = ob;
    }
}

__global__ void init_mm(unsigned* mm) {
    int t = threadIdx.x;
    if (t < 3) { mm[2 * t] = 0xFFFFFFFFu; mm[2 * t + 1] = 0u; }
}

// ---------------- MFMA GEMM (both operands row-major, k-fastest) ----------------
// out[b][m][n] = sum_c A[m][c] * Bt[b][n][c] + bias[m] (+resid)(+minmax)
template <bool MINMAX, bool RESID>
__global__ __launch_bounds__(256) void mgemm(const __bf16* __restrict__ A,   // [M][512]
                                             const __bf16* __restrict__ Bt,  // [8][1024][512]
                                             const float* __restrict__ bias,
                                             const float* __restrict__ resid,
                                             float* __restrict__ out,
                                             int M, unsigned* __restrict__ mm) {
    __shared__ __bf16 sA[128][72];
    __shared__ __bf16 sB[128][72];
    __shared__ float smn[4], smx[4];
    int tid = threadIdx.x;
    int l = tid & 63, w = tid >> 6;
    int lo = l & 15, hi = l >> 4;
    int mo = blockIdx.x, nt = blockIdx.y, b = blockIdx.z;
    const __bf16* Ap = A + (size_t)mo * 128 * 512;
    const __bf16* Bp = Bt + ((size_t)b * 1024 + (size_t)nt * 128) * 512;
    int m0 = (w >> 1) * 64, n0 = (w & 1) * 64;
    f32x4 acc[4][4] = {};

    for (int k0 = 0; k0 < 512; k0 += 64) {
        __syncthreads();
#pragma unroll
        for (int p = 0; p < 4; ++p) {
            int s = tid + p * 256;
            int row = s >> 3, ch = (s & 7) * 8;
            *(bf16x8*)&sA[row][ch] = *(const bf16x8*)(Ap + (size_t)row * 512 + k0 + ch);
            *(bf16x8*)&sB[row][ch] = *(const bf16x8*)(Bp + (size_t)row * 512 + k0 + ch);
        }
        __syncthreads();
#pragma unroll
        for (int kk = 0; kk < 2; ++kk) {
            int co = kk * 32 + hi * 8;
            bf16x8 af[4], bfr[4];
#pragma unroll
            for (int i = 0; i < 4; ++i) af[i]  = *(const bf16x8*)&sA[m0 + 16 * i + lo][co];
#pragma unroll
            for (int j = 0; j < 4; ++j) bfr[j] = *(const bf16x8*)&sB[n0 + 16 * j + lo][co];
#pragma unroll
            for (int i = 0; i < 4; ++i)
#pragma unroll
                for (int j = 0; j < 4; ++j) acc[i][j] = mfma16(af[i], bfr[j], acc[i][j]);
        }
    }

    float mn = 1e30f, mx = -1e30f;
    int gcol = nt * 128 + n0 + lo;
#pragma unroll
    for (int i = 0; i < 4; ++i) {
#pragma unroll
        for (int r = 0; r < 4; ++r) {
            int grow = mo * 128 + m0 + 16 * i + hi * 4 + r;
            float bi = bias[grow];
            size_t base = ((size_t)b * M + grow) * 1024 + gcol;
#pragma unroll
            for (int j = 0; j < 4; ++j) {
                float v = acc[i][j][r] + bi;
                if (MINMAX) { mn = fminf(mn, v); mx = fmaxf(mx, v); }
                if (RESID) v += resid[base + 16 * j];
                out[base + 16 * j] = v;
            }
        }
    }

    if (MINMAX) {
#pragma unroll
        for (int msk = 1; msk < 64; msk <<= 1) {
            mn = fminf(mn, __shfl_xor(mn, msk));
            mx = fmaxf(mx, __shfl_xor(mx, msk));
        }
        if (l == 0) { smn[w] = mn; smx[w] = mx; }
        __syncthreads();
        if (tid == 0) {
            mn = fminf(fminf(smn[0], smn[1]), fminf(smn[2], smn[3]));
            mx = fmaxf(fmaxf(smx[0], smx[1]), fmaxf(smx[2], smx[3]));
            int id = mo >> 2;  // 4 x 128-row tiles per tensor (q,k,v)
            atomicMin(&mm[2 * id], encf(mn));
            atomicMax(&mm[2 * id + 1], encf(mx));
        }
    }
}

// ---------------- MFMA flash attention ----------------
// grid 1024 (XCD-swizzled); block 256 = 4 waves; per block: one (b,h), 64 t-rows.
__global__ __launch_bounds__(256) void attn_mfma(const float* __restrict__ qkv,
                                                 const unsigned* __restrict__ mm,
                                                 __bf16* __restrict__ aT) {
    int f = blockIdx.x;
    int bh = (f & 7) * 8 + ((f >> 3) & 7);  // group 16 t-tiles of a head on one XCD
    int tt = f >> 6;
    int b = bh >> 3, hh = bh & 7;
    int t0 = tt * 64;
    const float* qg = qkv + (size_t)(b * 1536 + hh * 192) * 1024;
    const float* kg = qg + (size_t)64 * 1024;
    const float* vg = qg + (size_t)128 * 1024;

    float mn0 = fminf(decf(mm[0]), 0.f), mx0 = fmaxf(decf(mm[1]), 0.f);
    float qsc = fmaxf((mx0 - mn0) * (1.f / 255.f), 1e-8f), qzp = rintf(-mn0 / qsc);
    float mn1 = fminf(decf(mm[2]), 0.f), mx1 = fmaxf(decf(mm[3]), 0.f);
    float ksc = fmaxf((mx1 - mn1) * (1.f / 255.f), 1e-8f), kzp = rintf(-mn1 / ksc);
    float mn2 = fminf(decf(mm[4]), 0.f), mx2 = fmaxf(decf(mm[5]), 0.f);
    float vsc = fmaxf((mx2 - mn2) * (1.f / 255.f), 1e-8f), vzp = rintf(-mn2 / vsc);
    float inv_q = 1.f / qsc, inv_k = 1.f / ksc, inv_v = 1.f / vsc;
    float alpha = qsc * ksc * 0.125f;  // (1/sqrt(sqrt(64)))^2 = 1/8

    __shared__ __bf16 qT[64][72];      // [t_local][c]   integer-valued q
    __shared__ __bf16 kT[64][72];      // [s_local][c]   integer-valued k
    __shared__ __bf16 vL[64][72];      // [c][s_local]   integer-valued v
    __shared__ __bf16 pL[4][16][72];   // per-wave P [t_local16][s]

    int tid = threadIdx.x;
    int l = tid & 63, w = tid >> 6;
    int lo = l & 15, hi = l >> 4;
    int c0 = (tid >> 4) * 4;   // 0..60
    int tl = tid & 15;

    // stage qT (transpose, dequant to integer-valued bf16)
#pragma unroll
    for (int r = 0; r < 4; ++r) {
        int t = tl + 16 * r;
        float y0 = dqi(qg[(size_t)(c0 + 0) * 1024 + t0 + t], inv_q, qzp);
        float y1 = dqi(qg[(size_t)(c0 + 1) * 1024 + t0 + t], inv_q, qzp);
        float y2 = dqi(qg[(size_t)(c0 + 2) * 1024 + t0 + t], inv_q, qzp);
        float y3 = dqi(qg[(size_t)(c0 + 3) * 1024 + t0 + t], inv_q, qzp);
        bf16x4 o = {(__bf16)y0, (__bf16)y1, (__bf16)y2, (__bf16)y3};
        *(bf16x4*)&qT[t][c0] = o;
    }
    __syncthreads();
    bf16x8 qf0 = *(const bf16x8*)&qT[16 * w + lo][hi * 8];
    bf16x8 qf1 = *(const bf16x8*)&qT[16 * w + lo][32 + hi * 8];

    f32x4 acc0 = {}, acc1 = {}, acc2 = {}, acc3 = {};
    float m_run = -1e30f, l_run = 0.f;

    for (int st = 0; st < 16; ++st) {
        int s0 = st * 64;
        __syncthreads();
#pragma unroll
        for (int r = 0; r < 4; ++r) {
            int srow = tl + 16 * r;
            float y0 = dqi(kg[(size_t)(c0 + 0) * 1024 + s0 + srow], inv_k, kzp);
            float y1 = dqi(kg[(size_t)(c0 + 1) * 1024 + s0 + srow], inv_k, kzp);
            float y2 = dqi(kg[(size_t)(c0 + 2) * 1024 + s0 + srow], inv_k, kzp);
            float y3 = dqi(kg[(size_t)(c0 + 3) * 1024 + s0 + srow], inv_k, kzp);
            bf16x4 ok = {(__bf16)y0, (__bf16)y1, (__bf16)y2, (__bf16)y3};
            *(bf16x4*)&kT[srow][c0] = ok;
            int c = (tid >> 4) + 16 * r;
            float4 vv = *(const float4*)(vg + (size_t)c * 1024 + s0 + (tid & 15) * 4);
            bf16x4 ov = {(__bf16)dqi(vv.x, inv_v, vzp), (__bf16)dqi(vv.y, inv_v, vzp),
                         (__bf16)dqi(vv.z, inv_v, vzp), (__bf16)dqi(vv.w, inv_v, vzp)};
            *(bf16x4*)&vL[c][(tid & 15) * 4] = ov;
        }
        __syncthreads();

        // scores: D[s][t] = K·Q (A from kT, B = q frags); col(lane)=t, row=s
        f32x4 sf[4] = {};
#pragma unroll
        for (int sm = 0; sm < 4; ++sm)
            sf[sm] = mfma16(*(const bf16x8*)&kT[16 * sm + lo][hi * 8], qf0, sf[sm]);
#pragma unroll
        for (int sm = 0; sm < 4; ++sm)
            sf[sm] = mfma16(*(const bf16x8*)&kT[16 * sm + lo][32 + hi * 8], qf1, sf[sm]);

        // online softmax (t = lane-local)
        float tm = -1e30f;
#pragma unroll
        for (int sm = 0; sm < 4; ++sm)
#pragma unroll
            for (int r = 0; r < 4; ++r) { sf[sm][r] *= alpha; tm = fmaxf(tm, sf[sm][r]); }
        tm = fmaxf(tm, __shfl_xor(tm, 16));
        tm = fmaxf(tm, __shfl_xor(tm, 32));
        float mnew = fmaxf(m_run, tm);
        float ts = 0.f;
#pragma unroll
        for (int sm = 0; sm < 4; ++sm)
#pragma unroll
            for (int r = 0; r < 4; ++r) {
                float p = __expf(sf[sm][r] - mnew);
                sf[sm][r] = p;
                ts += p;
            }
        ts += __shfl_xor(ts, 16);
        ts += __shfl_xor(ts, 32);
        float fr = __expf(m_run - mnew);
        l_run = l_run * fr + ts;
        m_run = mnew;
        acc0 *= fr; acc1 *= fr; acc2 *= fr; acc3 *= fr;

        // P -> LDS (per-wave, bf16)
#pragma unroll
        for (int sm = 0; sm < 4; ++sm) {
            bf16x4 pb = {(__bf16)sf[sm][0], (__bf16)sf[sm][1], (__bf16)sf[sm][2], (__bf16)sf[sm][3]};
            *(bf16x4*)&pL[w][lo][16 * sm + hi * 4] = pb;
        }
        // PV: D[c][t] += V·P
        bf16x8 pf0 = *(const bf16x8*)&pL[w][lo][hi * 8];
        bf16x8 pf1 = *(const bf16x8*)&pL[w][lo][32 + hi * 8];
        acc0 = mfma16(*(const bf16x8*)&vL[lo][hi * 8], pf0, acc0);
        acc1 = mfma16(*(const bf16x8*)&vL[16 + lo][hi * 8], pf0, acc1);
        acc2 = mfma16(*(const bf16x8*)&vL[32 + lo][hi * 8], pf0, acc2);
        acc3 = mfma16(*(const bf16x8*)&vL[48 + lo][hi * 8], pf0, acc3);
        acc0 = mfma16(*(const bf16x8*)&vL[lo][32 + hi * 8], pf1, acc0);
        acc1 = mfma16(*(const bf16x8*)&vL[16 + lo][32 + hi * 8], pf1, acc1);
        acc2 = mfma16(*(const bf16x8*)&vL[32 + lo][32 + hi * 8], pf1, acc2);
        acc3 = mfma16(*(const bf16x8*)&vL[48 + lo][32 + hi * 8], pf1, acc3);
    }

    float rl = vsc / l_run;
    __syncthreads();
    {
        bf16x4 o0 = {(__bf16)(acc0[0] * rl), (__bf16)(acc0[1] * rl), (__bf16)(acc0[2] * rl), (__bf16)(acc0[3] * rl)};
        bf16x4 o1 = {(__bf16)(acc1[0] * rl), (__bf16)(acc1[1] * rl), (__bf16)(acc1[2] * rl), (__bf16)(acc1[3] * rl)};
        bf16x4 o2 = {(__bf16)(acc2[0] * rl), (__bf16)(acc2[1] * rl), (__bf16)(acc2[2] * rl), (__bf16)(acc2[3] * rl)};
        bf16x4 o3 = {(__bf16)(acc3[0] * rl), (__bf16)(acc3[1] * rl), (__bf16)(acc3[2] * rl), (__bf16)(acc3[3] * rl)};
        *(bf16x4*)&qT[16 * w + lo][0  + hi * 4] = o0;
        *(bf16x4*)&qT[16 * w + lo][16 + hi * 4] = o1;
        *(bf16x4*)&qT[16 * w + lo][32 + hi * 4] = o2;
        *(bf16x4*)&qT[16 * w + lo][48 + hi * 4] = o3;
    }
    __syncthreads();
    __bf16* ap = aT + ((size_t)b * 1024 + t0 + (tid >> 2)) * 512 + hh * 64;
    bf16x8 v0 = *(const bf16x8*)&qT[tid >> 2][(tid & 3) * 8];
    bf16x8 v1 = *(const bf16x8*)&qT[tid >> 2][32 + (tid & 3) * 8];
    *(bf16x8*)(ap + (tid & 3) * 8) = v0;
    *(bf16x8*)(ap + 32 + (tid & 3) * 8) = v1;
}

extern "C" void kernel_launch(void* const* d_in, const int* in_sizes, int n_in,
                              void* d_out, int out_size, void* d_ws, size_t ws_size,
                              hipStream_t stream) {
    const float* x      = (const float*)d_in[0];
    const float* gn_w   = (const float*)d_in[1];
    const float* gn_b   = (const float*)d_in[2];
    const float* qkv_w  = (const float*)d_in[3];
    const float* qkv_b  = (const float*)d_in[4];
    const float* proj_w = (const float*)d_in[5];
    const float* proj_b = (const float*)d_in[6];
    char* ws = (char*)d_ws;
    float*    qkv = (float*)(ws + QKV_OFF);
    __bf16*   hT  = (__bf16*)(ws + HT_OFF);   // hT, later reused as aT
    __bf16*   wq  = (__bf16*)(ws + WQ_OFF);
    __bf16*   wp  = (__bf16*)(ws + WP_OFF);
    unsigned* mm  = (unsigned*)(ws + MM_OFF);
    float* out = (float*)d_out;

    conv_bf16<<<768, 256, 0, stream>>>(qkv_w, wq, 196608);
    conv_bf16<<<256, 256, 0, stream>>>(proj_w, wp, 65536);
    gn_kernel<<<256, 256, 0, stream>>>(x, gn_w, gn_b, hT);
    init_mm<<<1, 64, 0, stream>>>(mm);
    mgemm<true, false><<<dim3(12, 8, 8), 256, 0, stream>>>(wq, hT, qkv_b, nullptr, qkv, 1536, mm);
    attn_mfma<<<1024, 256, 0, stream>>>(qkv, mm, hT);
    mgemm<false, true><<<dim3(4, 8, 8), 256, 0, stream>>>(wp, hT, proj_b, x, out, 512, nullptr);
}